// Round 5
// baseline (323.008 us; speedup 1.0000x reference)
//
#include <hip/hip_runtime.h>
#include <cstdint>
#include <cstddef>

#define SEQ   2048
#define BBAT  2
#define EMBED 512
#define NH    8
#define HD    64
#define NPOS  34

typedef __bf16 bf16;
typedef __bf16 bf16x8 __attribute__((ext_vector_type(8)));
typedef float  f32x4  __attribute__((ext_vector_type(4)));

// scale = log2(e)/8 : energy=(qk+bias)/8, computed in exp2 domain
#define ESCALE 0.1803368801111204f

__device__ __forceinline__ f32x4 mfma16(bf16x8 a, bf16x8 b, f32x4 c){
  return __builtin_amdgcn_mfma_f32_16x16x32_bf16(a, b, c, 0, 0, 0);
}

// ---------------- kernel 1: fused prep ----------------
__global__ __launch_bounds__(256) void k_prep(
    const float* __restrict__ Q, const float* __restrict__ K, const float* __restrict__ V,
    const float* __restrict__ Wq, const float* __restrict__ Wk,
    const float* __restrict__ Wv, const float* __restrict__ Wo,
    const float* __restrict__ RE,
    bf16* __restrict__ Qb, bf16* __restrict__ Kb, bf16* __restrict__ Vb,
    bf16* __restrict__ Wall, bf16* __restrict__ Rb)
{
  const int NCONV = 3*524288;
  const int NW = 196608, NO = 262144;
  int i = blockIdx.x*256 + threadIdx.x;
  if (i < NCONV){
    int tsel = i >> 19, j = i & 524287;
    const float* s = tsel==0 ? Q : (tsel==1 ? K : V);
    bf16* d       = tsel==0 ? Qb : (tsel==1 ? Kb : Vb);
    float4 v = ((const float4*)s)[j];
    union { bf16 e[4]; ushort4 u; } pk;
    pk.e[0]=(bf16)v.x; pk.e[1]=(bf16)v.y; pk.e[2]=(bf16)v.z; pk.e[3]=(bf16)v.w;
    ((ushort4*)d)[j] = pk.u;
  } else {
    int j = i - NCONV;
    if (j < NW){
      int w  = j >> 16;
      int r  = j & 65535;
      int np = r >> 7, c4 = (r & 127) << 2;
      const float* W = (w==0) ? Wq : ((w==1) ? Wk : Wv);
      int src = ((np & 63) << 3) + (np >> 6);
      float4 v = *(const float4*)(W + (size_t)src*512 + c4);
      union { bf16 e[4]; ushort4 u; } pk;
      pk.e[0]=(bf16)v.x; pk.e[1]=(bf16)v.y; pk.e[2]=(bf16)v.z; pk.e[3]=(bf16)v.w;
      *(ushort4*)(Wall + (size_t)w*262144 + (size_t)np*512 + c4) = pk.u;
    } else if (j < NW + NO){
      int jj = j - NW;
      int n = jj >> 9, kp = jj & 511;
      int src = ((kp & 63) << 3) + (kp >> 6);
      Wall[(size_t)3*262144 + (size_t)n*512 + kp] = (bf16)Wo[(size_t)n*512 + src];
    } else {
      int jj = j - NW - NO;
      if (jj < 8*48*64){
        int h  = jj / (48*64);
        int r2 = jj - h*(48*64);
        int p  = r2 >> 6, dd = r2 & 63;
        float v = (p < NPOS) ? RE[(size_t)p*512 + dd*8 + h] : 0.f;
        Rb[jj] = (bf16)v;
      }
    }
  }
}

// ---------------- GEMM 128x64 tile (projections) ----------------
__global__ __launch_bounds__(256,2) void k_gemm_proj(
    const bf16* __restrict__ Qb, const bf16* __restrict__ Kb, const bf16* __restrict__ Vb,
    const bf16* __restrict__ W,  bf16* __restrict__ Qp, bf16* __restrict__ Kp, bf16* __restrict__ Vp)
{
  const bf16* A  = blockIdx.z==0 ? Qb : (blockIdx.z==1 ? Kb : Vb);
  const bf16* Bw = W + (size_t)blockIdx.z*262144;
  bf16* C        = blockIdx.z==0 ? Qp : (blockIdx.z==1 ? Kp : Vp);

  __shared__ __align__(16) bf16 As[128][72];
  __shared__ __align__(16) bf16 Bs[64][72];
  const int t = threadIdx.x;
  const int w = t >> 6, lane = t & 63, l15 = lane & 15, quad = lane >> 4;
  const int wm = (w & 1) * 64, wn = (w >> 1) * 32;
  const int m0 = blockIdx.y * 128, n0 = blockIdx.x * 64;

  f32x4 acc[4][2];
  #pragma unroll
  for (int mt=0; mt<4; ++mt)
    #pragma unroll
    for (int nt=0; nt<2; ++nt) acc[mt][nt] = (f32x4){0.f,0.f,0.f,0.f};

  for (int kt = 0; kt < 512; kt += 64){
    #pragma unroll
    for (int i = 0; i < 4; ++i){
      int lin = t + 256*i;
      int r = lin >> 3, c8 = (lin & 7) << 3;
      *(uint4*)&As[r][c8] = *(const uint4*)(A + (size_t)(m0 + r)*512 + kt + c8);
    }
    #pragma unroll
    for (int i = 0; i < 2; ++i){
      int lin = t + 256*i;
      int r = lin >> 3, c8 = (lin & 7) << 3;
      *(uint4*)&Bs[r][c8] = *(const uint4*)(Bw + (size_t)(n0 + r)*512 + kt + c8);
    }
    __syncthreads();
    #pragma unroll
    for (int ks = 0; ks < 2; ++ks){
      bf16x8 am[4], bn[2];
      #pragma unroll
      for (int x=0;x<4;++x) am[x] = *(const bf16x8*)&As[wm + x*16 + l15][ks*32 + quad*8];
      #pragma unroll
      for (int y=0;y<2;++y) bn[y] = *(const bf16x8*)&Bs[wn + y*16 + l15][ks*32 + quad*8];
      #pragma unroll
      for (int mt=0;mt<4;++mt)
        #pragma unroll
        for (int nt=0;nt<2;++nt)
          acc[mt][nt] = mfma16(am[mt], bn[nt], acc[mt][nt]);
    }
    __syncthreads();
  }
  #pragma unroll
  for (int mt=0;mt<4;++mt)
    #pragma unroll
    for (int r=0;r<4;++r){
      int m = m0 + wm + mt*16 + quad*4 + r;
      #pragma unroll
      for (int nt=0;nt<2;++nt)
        C[(size_t)m*512 + n0 + wn + nt*16 + l15] = (bf16)acc[mt][nt][r];
    }
}

// ---------------- GEMM 64x64 tile (output proj, f32 out) ----------------
__global__ __launch_bounds__(256,2) void k_gemm_out(
    const bf16* __restrict__ A, const bf16* __restrict__ Bw, float* __restrict__ C)
{
  __shared__ __align__(16) bf16 As[64][72];
  __shared__ __align__(16) bf16 Bs[64][72];
  const int t = threadIdx.x;
  const int w = t >> 6, lane = t & 63, l15 = lane & 15, quad = lane >> 4;
  const int wm = (w & 1) * 32, wn = (w >> 1) * 32;
  const int m0 = blockIdx.y * 64, n0 = blockIdx.x * 64;

  f32x4 acc[2][2];
  #pragma unroll
  for (int mt=0; mt<2; ++mt)
    #pragma unroll
    for (int nt=0; nt<2; ++nt) acc[mt][nt] = (f32x4){0.f,0.f,0.f,0.f};

  for (int kt = 0; kt < 512; kt += 64){
    #pragma unroll
    for (int i = 0; i < 2; ++i){
      int lin = t + 256*i;
      int r = lin >> 3, c8 = (lin & 7) << 3;
      *(uint4*)&As[r][c8] = *(const uint4*)(A  + (size_t)(m0 + r)*512 + kt + c8);
      *(uint4*)&Bs[r][c8] = *(const uint4*)(Bw + (size_t)(n0 + r)*512 + kt + c8);
    }
    __syncthreads();
    #pragma unroll
    for (int ks = 0; ks < 2; ++ks){
      bf16x8 am[2], bn[2];
      #pragma unroll
      for (int x=0;x<2;++x) am[x] = *(const bf16x8*)&As[wm + x*16 + l15][ks*32 + quad*8];
      #pragma unroll
      for (int y=0;y<2;++y) bn[y] = *(const bf16x8*)&Bs[wn + y*16 + l15][ks*32 + quad*8];
      #pragma unroll
      for (int mt=0;mt<2;++mt)
        #pragma unroll
        for (int nt=0;nt<2;++nt)
          acc[mt][nt] = mfma16(am[mt], bn[nt], acc[mt][nt]);
    }
    __syncthreads();
  }
  #pragma unroll
  for (int mt=0;mt<2;++mt)
    #pragma unroll
    for (int r=0;r<4;++r){
      int m = m0 + wm + mt*16 + quad*4 + r;
      #pragma unroll
      for (int nt=0;nt<2;++nt)
        C[(size_t)m*512 + n0 + wn + nt*16 + l15] = acc[mt][nt][r];
    }
}

// ---------------- fused: V transpose + expw (bf16, stride 64) ----------------
__global__ __launch_bounds__(256) void k_mid(
    const bf16* __restrict__ Vp, const bf16* __restrict__ Qp,
    const bf16* __restrict__ Rb, bf16* __restrict__ Vt, bf16* __restrict__ expw)
{
  __shared__ bf16 T[64][68];
  const int b = blockIdx.z, h = blockIdx.y, s0 = blockIdx.x*64;
  const int t = threadIdx.x;
  // --- transpose (b,s,h,d) -> (b,h,d,s) ---
  #pragma unroll
  for (int i = 0; i < 4; ++i){
    int lin = t + 256*i;
    int sl = lin >> 4, d4 = (lin & 15) << 2;
    ushort4 v = *(const ushort4*)(Vp + (size_t)(b*SEQ + s0 + sl)*EMBED + h*HD + d4);
    union { ushort4 u; bf16 e[4]; } pk; pk.u = v;
    T[d4+0][sl] = pk.e[0]; T[d4+1][sl] = pk.e[1];
    T[d4+2][sl] = pk.e[2]; T[d4+3][sl] = pk.e[3];
  }
  __syncthreads();
  {
    const int d = t >> 2, c = (t & 3) * 16;
    bf16* dst = Vt + ((size_t)((b*NH + h)*HD + d))*SEQ + s0 + c;
    #pragma unroll
    for (int i = 0; i < 4; ++i){
      union { ushort4 u; bf16 e[4]; } pk;
      pk.e[0]=T[d][c+i*4+0]; pk.e[1]=T[d][c+i*4+1];
      pk.e[2]=T[d][c+i*4+2]; pk.e[3]=T[d][c+i*4+3];
      *(ushort4*)(dst + i*4) = pk.u;
    }
  }
  // --- expw: exp2(Qrel*ESCALE), p=0 -> 0 ; bf16, row stride 64 ---
  const int w = t >> 6, lane = t & 63, l15 = lane & 15, quad = lane >> 4;
  const bf16* qrow = Qp + (size_t)(b*SEQ + s0 + w*16 + l15)*EMBED + h*HD;
  bf16x8 aq0 = *(const bf16x8*)(qrow + quad*8);
  bf16x8 aq1 = *(const bf16x8*)(qrow + 32 + quad*8);
  const bf16* rh = Rb + h*3072;
  #pragma unroll
  for (int nt = 0; nt < 3; ++nt){
    bf16x8 b0 = *(const bf16x8*)(rh + (nt*16 + l15)*64 + quad*8);
    bf16x8 b1 = *(const bf16x8*)(rh + (nt*16 + l15)*64 + 32 + quad*8);
    f32x4 c = (f32x4){0.f,0.f,0.f,0.f};
    c = mfma16(aq0, b0, c);
    c = mfma16(aq1, b1, c);
    int p = nt*16 + l15;
    if (p < 36){
      #pragma unroll
      for (int r = 0; r < 4; ++r){
        int q = s0 + w*16 + quad*4 + r;
        float v = (p == 0 || p >= NPOS) ? 0.f : exp2f(c[r]*ESCALE);
        expw[(((size_t)((b*NH + h)*SEQ) + q) << 6) + p] = (bf16)v;
      }
    }
  }
}

// ---------------- flash attention with relative-position bias ----------------
// grid (32,8,2) x 256 thr (4 waves, 16 q-rows each, wave-private 16q x 128k tiles).
// ALL global inputs (ids, K, V) register-prefetched one 128-k tile ahead;
// expw gathered from bf16 table (L1-resident) using prefetched ids.
__global__ __launch_bounds__(256,3) void k_attn(
    const bf16* __restrict__ Qp, const bf16* __restrict__ Kp,
    const bf16* __restrict__ Vt, const bf16* __restrict__ expw,
    const int* __restrict__ ids, bf16* __restrict__ Out)
{
  // LDS 53248 B -> 3 WG/CU
  __shared__ __align__(16) bf16 Ks[128][72];
  __shared__ __align__(16) bf16 Vs[64][136];
  __shared__ __align__(16) bf16 Ps[64][136];

  const int t = threadIdx.x;
  const int b = blockIdx.z, h = blockIdx.y;
  const int q0 = blockIdx.x * 64;
  const int w = t >> 6, lane = t & 63, l15 = lane & 15, quad = lane >> 4;
  const int qb = w*16 + quad*4;

  // Q A-frags straight from global (L2-resident)
  const bf16* qrow = Qp + (size_t)(b*SEQ + q0 + w*16 + l15)*EMBED + h*HD;
  bf16x8 aq0 = *(const bf16x8*)(qrow + quad*8);
  bf16x8 aq1 = *(const bf16x8*)(qrow + 32 + quad*8);

  const bf16* kbase = Kp + (size_t)b*SEQ*EMBED + h*HD;
  const bf16* vbase = Vt + (size_t)(b*NH + h)*HD*SEQ;
  const int*  idp   = ids + (size_t)b*SEQ*SEQ + (size_t)(q0 + qb)*SEQ + l15;
  const bf16* ewp   = expw + (((size_t)((b*NH + h)*SEQ) + q0 + qb) << 6);

  // ---- stage tile 0: K(128x64), V^T(64x128) via regs; ids via 32 dwords ----
  uint4 pk[4], pv[4];
  int nid[8][4];
  #pragma unroll
  for (int i = 0; i < 4; ++i){
    int lin = t + 256*i;
    { int r = lin >> 3, c8 = (lin & 7) << 3;
      pk[i] = *(const uint4*)(kbase + (size_t)r*EMBED + c8); }
    { int d = lin >> 4, c8 = (lin & 15) << 3;
      pv[i] = *(const uint4*)(vbase + (size_t)d*SEQ + c8); }
  }
  #pragma unroll
  for (int ct = 0; ct < 8; ++ct)
    #pragma unroll
    for (int r = 0; r < 4; ++r)
      nid[ct][r] = idp[(size_t)r*SEQ + ct*16];
  #pragma unroll
  for (int i = 0; i < 4; ++i){
    int lin = t + 256*i;
    { int r = lin >> 3, c8 = (lin & 7) << 3; *(uint4*)&Ks[r][c8] = pk[i]; }
    { int d = lin >> 4, c8 = (lin & 15) << 3; *(uint4*)&Vs[d][c8] = pv[i]; }
  }
  __syncthreads();

  f32x4 acc[4];
  #pragma unroll
  for (int nt=0;nt<4;++nt) acc[nt] = (f32x4){0.f,0.f,0.f,0.f};
  float lsum[4] = {0.f,0.f,0.f,0.f};

  for (int kt = 0; kt < 16; ++kt){
    const bool hasNext = (kt < 15);
    const int kn = (kt + 1) * 128;

    // ---- 1. expw gathers for CURRENT tile (indices already resident) ----
    float wv[8][4];
    #pragma unroll
    for (int ct = 0; ct < 8; ++ct)
      #pragma unroll
      for (int r = 0; r < 4; ++r)
        wv[ct][r] = (float)ewp[((size_t)r << 6) + nid[ct][r]];

    // ---- 2. prefetch NEXT tile ids ----
    if (hasNext){
      #pragma unroll
      for (int ct = 0; ct < 8; ++ct)
        #pragma unroll
        for (int r = 0; r < 4; ++r)
          nid[ct][r] = idp[(size_t)r*SEQ + kn + ct*16];
    }
    // ---- 3. prefetch NEXT tile K ----
    if (hasNext){
      #pragma unroll
      for (int i = 0; i < 4; ++i){
        int lin = t + 256*i;
        int r = lin >> 3, c8 = (lin & 7) << 3;
        pk[i] = *(const uint4*)(kbase + (size_t)(kn + r)*EMBED + c8);
      }
    }

    // ---- 4. QK: 16q x 128k per wave ----
    f32x4 sf[8];
    #pragma unroll
    for (int ct = 0; ct < 8; ++ct){
      bf16x8 bk0 = *(const bf16x8*)&Ks[ct*16 + l15][quad*8];
      bf16x8 bk1 = *(const bf16x8*)&Ks[ct*16 + l15][32 + quad*8];
      f32x4 c = (f32x4){0.f,0.f,0.f,0.f};
      c = mfma16(aq0, bk0, c);
      c = mfma16(aq1, bk1, c);
      sf[ct] = c;
    }

    // ---- 5. p = exp2(s*ESCALE)*wgt ; Ps (wave-private rows) ----
    #pragma unroll
    for (int ct = 0; ct < 8; ++ct)
      #pragma unroll
      for (int r = 0; r < 4; ++r){
        float p = exp2f(sf[ct][r]*ESCALE) * wv[ct][r];
        lsum[r] += p;
        Ps[qb + r][ct*16 + l15] = (bf16)p;
      }

    // ---- 6. prefetch NEXT tile V ----
    if (hasNext){
      #pragma unroll
      for (int i = 0; i < 4; ++i){
        int lin = t + 256*i;
        int d = lin >> 4, c8 = (lin & 15) << 3;
        pv[i] = *(const uint4*)(vbase + (size_t)d*SEQ + kn + c8);
      }
    }

    // ---- 7. PV: O += P*V (own Ps rows; no cross-wave barrier) ----
    #pragma unroll
    for (int kk = 0; kk < 4; ++kk){
      bf16x8 ap = *(const bf16x8*)&Ps[w*16 + l15][kk*32 + quad*8];
      #pragma unroll
      for (int nt = 0; nt < 4; ++nt){
        bf16x8 bv = *(const bf16x8*)&Vs[nt*16 + l15][kk*32 + quad*8];
        acc[nt] = mfma16(ap, bv, acc[nt]);
      }
    }
    __syncthreads();

    // ---- 8. write prefetched K/V to LDS ----
    if (hasNext){
      #pragma unroll
      for (int i = 0; i < 4; ++i){
        int lin = t + 256*i;
        { int r = lin >> 3, c8 = (lin & 7) << 3; *(uint4*)&Ks[r][c8] = pk[i]; }
        { int d = lin >> 4, c8 = (lin & 15) << 3; *(uint4*)&Vs[d][c8] = pv[i]; }
      }
      __syncthreads();
    }
  }

  // ---- epilogue: reduce lsum over l15, normalize, store bf16 ----
  #pragma unroll
  for (int r=0;r<4;++r){
    lsum[r] += __shfl_xor(lsum[r], 1);
    lsum[r] += __shfl_xor(lsum[r], 2);
    lsum[r] += __shfl_xor(lsum[r], 4);
    lsum[r] += __shfl_xor(lsum[r], 8);
    float inv = 1.f / lsum[r];
    int q = q0 + qb + r;
    #pragma unroll
    for (int nt=0;nt<4;++nt){
      int d = nt*16 + l15;
      Out[(size_t)(b*SEQ + q)*EMBED + h*HD + d] = (bf16)(acc[nt][r]*inv);
    }
  }
}

// ---------------- launch ----------------
extern "C" void kernel_launch(void* const* d_in, const int* in_sizes, int n_in,
                              void* d_out, int out_size, void* d_ws, size_t ws_size,
                              hipStream_t stream)
{
  (void)in_sizes; (void)n_in; (void)out_size;
  const float* Q  = (const float*)d_in[0];
  const float* K  = (const float*)d_in[1];
  const float* V  = (const float*)d_in[2];
  const int*   ID = (const int*)d_in[3];
  const float* Wq = (const float*)d_in[4];
  const float* Wk = (const float*)d_in[5];
  const float* Wv = (const float*)d_in[6];
  const float* Wo = (const float*)d_in[7];
  const float* RE = (const float*)d_in[8];
  float* out = (float*)d_out;

  const size_t MB = (size_t)1 << 20;
  if (ws_size < 36*MB) return;
  char* ws = (char*)d_ws;
  bf16*  Qb    = (bf16*)(ws + 0*MB);             // -> Vt overlay after proj
  bf16*  Kb    = (bf16*)(ws + 4*MB);             // -> AO overlay after attn-input ready
  bf16*  Vb    = (bf16*)(ws + 8*MB);
  bf16*  Qp    = (bf16*)(ws + 12*MB);
  bf16*  Kp    = (bf16*)(ws + 16*MB);
  bf16*  Vp    = (bf16*)(ws + 20*MB);
  bf16*  Wall  = (bf16*)(ws + 24*MB);            // 2 MB (Wq',Wk',Wv',Wo')
  bf16*  Wop   = Wall + (size_t)3*262144;
  bf16*  expw  = (bf16*)(ws + 26*MB);            // 2*8*2048*64*2 = 4 MB
  bf16*  Rb    = (bf16*)(ws + 30*MB);            // 48 KB
  bf16*  Vt    = (bf16*)(ws + 0*MB);
  bf16*  AO    = (bf16*)(ws + 4*MB);

  k_prep      <<<dim3(8032),    256, 0, stream>>>(Q, K, V, Wq, Wk, Wv, Wo, RE,
                                                  Qb, Kb, Vb, Wall, Rb);
  k_gemm_proj <<<dim3(8,32,3),  256, 0, stream>>>(Qb, Kb, Vb, Wall, Qp, Kp, Vp);
  k_mid       <<<dim3(32,8,2),  256, 0, stream>>>(Vp, Qp, Rb, Vt, expw);
  k_attn      <<<dim3(32,8,2),  256, 0, stream>>>(Qp, Kp, Vt, expw, ID, AO);
  k_gemm_out  <<<dim3(8,64),    256, 0, stream>>>(AO, Wop, out);
}

// Round 6
// 192.855 us; speedup vs baseline: 1.6749x; 1.6749x over previous
//
#include <hip/hip_runtime.h>
#include <cstdint>
#include <cstddef>

#define SEQ   2048
#define BBAT  2
#define EMBED 512
#define NH    8
#define HD    64
#define NPOS  34

typedef __bf16 bf16;
typedef __bf16 bf16x8 __attribute__((ext_vector_type(8)));
typedef float  f32x4  __attribute__((ext_vector_type(4)));

// scale = log2(e)/8 : energy=(qk+bias)/8, computed in exp2 domain
#define ESCALE 0.1803368801111204f

__device__ __forceinline__ f32x4 mfma16(bf16x8 a, bf16x8 b, f32x4 c){
  return __builtin_amdgcn_mfma_f32_16x16x32_bf16(a, b, c, 0, 0, 0);
}

// ---------------- kernel 1: fused prep ----------------
// A: fp32->bf16 convert Q,K,V ; B: weight perms ; C: rel_emb permute (48-row pad)
__global__ __launch_bounds__(256) void k_prep(
    const float* __restrict__ Q, const float* __restrict__ K, const float* __restrict__ V,
    const float* __restrict__ Wq, const float* __restrict__ Wk,
    const float* __restrict__ Wv, const float* __restrict__ Wo,
    const float* __restrict__ RE,
    bf16* __restrict__ Qb, bf16* __restrict__ Kb, bf16* __restrict__ Vb,
    bf16* __restrict__ Wall, bf16* __restrict__ Rb)
{
  const int NCONV = 3*524288;
  const int NW = 196608, NO = 262144;
  int i = blockIdx.x*256 + threadIdx.x;
  if (i < NCONV){
    int tsel = i >> 19, j = i & 524287;
    const float* s = tsel==0 ? Q : (tsel==1 ? K : V);
    bf16* d       = tsel==0 ? Qb : (tsel==1 ? Kb : Vb);
    float4 v = ((const float4*)s)[j];
    union { bf16 e[4]; ushort4 u; } pk;
    pk.e[0]=(bf16)v.x; pk.e[1]=(bf16)v.y; pk.e[2]=(bf16)v.z; pk.e[3]=(bf16)v.w;
    ((ushort4*)d)[j] = pk.u;
  } else {
    int j = i - NCONV;
    if (j < NW){
      int w  = j >> 16;
      int r  = j & 65535;
      int np = r >> 7, c4 = (r & 127) << 2;
      const float* W = (w==0) ? Wq : ((w==1) ? Wk : Wv);
      int src = ((np & 63) << 3) + (np >> 6);
      float4 v = *(const float4*)(W + (size_t)src*512 + c4);
      union { bf16 e[4]; ushort4 u; } pk;
      pk.e[0]=(bf16)v.x; pk.e[1]=(bf16)v.y; pk.e[2]=(bf16)v.z; pk.e[3]=(bf16)v.w;
      *(ushort4*)(Wall + (size_t)w*262144 + (size_t)np*512 + c4) = pk.u;
    } else if (j < NW + NO){
      int jj = j - NW;
      int n = jj >> 9, kp = jj & 511;
      int src = ((kp & 63) << 3) + (kp >> 6);
      Wall[(size_t)3*262144 + (size_t)n*512 + kp] = (bf16)Wo[(size_t)n*512 + src];
    } else {
      int jj = j - NW - NO;
      if (jj < 8*48*64){
        int h  = jj / (48*64);
        int r2 = jj - h*(48*64);
        int p  = r2 >> 6, dd = r2 & 63;
        float v = (p < NPOS) ? RE[(size_t)p*512 + dd*8 + h] : 0.f;
        Rb[jj] = (bf16)v;
      }
    }
  }
}

// ---------------- GEMM 128x64 tile (projections); z==2 writes V transposed ----------------
__global__ __launch_bounds__(256,2) void k_gemm_proj(
    const bf16* __restrict__ Qb, const bf16* __restrict__ Kb, const bf16* __restrict__ Vb,
    const bf16* __restrict__ W,  bf16* __restrict__ Qp, bf16* __restrict__ Kp, bf16* __restrict__ Vt)
{
  const bf16* A  = blockIdx.z==0 ? Qb : (blockIdx.z==1 ? Kb : Vb);
  const bf16* Bw = W + (size_t)blockIdx.z*262144;

  __shared__ __align__(16) bf16 As[128][72];
  __shared__ __align__(16) bf16 Bs[64][72];
  const int t = threadIdx.x;
  const int w = t >> 6, lane = t & 63, l15 = lane & 15, quad = lane >> 4;
  const int wm = (w & 1) * 64, wn = (w >> 1) * 32;
  const int m0 = blockIdx.y * 128, n0 = blockIdx.x * 64;

  f32x4 acc[4][2];
  #pragma unroll
  for (int mt=0; mt<4; ++mt)
    #pragma unroll
    for (int nt=0; nt<2; ++nt) acc[mt][nt] = (f32x4){0.f,0.f,0.f,0.f};

  for (int kt = 0; kt < 512; kt += 64){
    #pragma unroll
    for (int i = 0; i < 4; ++i){
      int lin = t + 256*i;
      int r = lin >> 3, c8 = (lin & 7) << 3;
      *(uint4*)&As[r][c8] = *(const uint4*)(A + (size_t)(m0 + r)*512 + kt + c8);
    }
    #pragma unroll
    for (int i = 0; i < 2; ++i){
      int lin = t + 256*i;
      int r = lin >> 3, c8 = (lin & 7) << 3;
      *(uint4*)&Bs[r][c8] = *(const uint4*)(Bw + (size_t)(n0 + r)*512 + kt + c8);
    }
    __syncthreads();
    #pragma unroll
    for (int ks = 0; ks < 2; ++ks){
      bf16x8 am[4], bn[2];
      #pragma unroll
      for (int x=0;x<4;++x) am[x] = *(const bf16x8*)&As[wm + x*16 + l15][ks*32 + quad*8];
      #pragma unroll
      for (int y=0;y<2;++y) bn[y] = *(const bf16x8*)&Bs[wn + y*16 + l15][ks*32 + quad*8];
      #pragma unroll
      for (int mt=0;mt<4;++mt)
        #pragma unroll
        for (int nt=0;nt<2;++nt)
          acc[mt][nt] = mfma16(am[mt], bn[nt], acc[mt][nt]);
    }
    __syncthreads();
  }

  if (blockIdx.z != 2){
    bf16* C = blockIdx.z==0 ? Qp : Kp;
    #pragma unroll
    for (int mt=0;mt<4;++mt)
      #pragma unroll
      for (int r=0;r<4;++r){
        int m = m0 + wm + mt*16 + quad*4 + r;
        #pragma unroll
        for (int nt=0;nt<2;++nt)
          C[(size_t)m*512 + n0 + wn + nt*16 + l15] = (bf16)acc[mt][nt][r];
      }
  } else {
    // transpose in-LDS (As region), then coalesced store to Vt (b,h,d,s)
    bf16 (*VT)[136] = (bf16(*)[136])As;    // 64 x 136 bf16 = 17408 B <= 18432
    #pragma unroll
    for (int mt=0;mt<4;++mt)
      #pragma unroll
      for (int r=0;r<4;++r){
        int m = wm + mt*16 + quad*4 + r;
        #pragma unroll
        for (int nt=0;nt<2;++nt)
          VT[wn + nt*16 + l15][m] = (bf16)acc[mt][nt][r];
      }
    __syncthreads();
    const int h = blockIdx.x, b = m0 >> 11, s0 = m0 & 2047;
    const int n = t >> 2, c0 = (t & 3) * 32;
    bf16* dst = Vt + ((size_t)((b*NH + h)*HD + n))*SEQ + s0 + c0;
    #pragma unroll
    for (int i = 0; i < 4; ++i)
      *(uint4*)(dst + i*8) = *(const uint4*)&VT[n][c0 + i*8];
  }
}

// ---------------- GEMM 64x64 tile (output proj, f32 out) ----------------
__global__ __launch_bounds__(256,2) void k_gemm_out(
    const bf16* __restrict__ A, const bf16* __restrict__ Bw, float* __restrict__ C)
{
  __shared__ __align__(16) bf16 As[64][72];
  __shared__ __align__(16) bf16 Bs[64][72];
  const int t = threadIdx.x;
  const int w = t >> 6, lane = t & 63, l15 = lane & 15, quad = lane >> 4;
  const int wm = (w & 1) * 32, wn = (w >> 1) * 32;
  const int m0 = blockIdx.y * 64, n0 = blockIdx.x * 64;

  f32x4 acc[2][2];
  #pragma unroll
  for (int mt=0; mt<2; ++mt)
    #pragma unroll
    for (int nt=0; nt<2; ++nt) acc[mt][nt] = (f32x4){0.f,0.f,0.f,0.f};

  for (int kt = 0; kt < 512; kt += 64){
    #pragma unroll
    for (int i = 0; i < 2; ++i){
      int lin = t + 256*i;
      int r = lin >> 3, c8 = (lin & 7) << 3;
      *(uint4*)&As[r][c8] = *(const uint4*)(A  + (size_t)(m0 + r)*512 + kt + c8);
      *(uint4*)&Bs[r][c8] = *(const uint4*)(Bw + (size_t)(n0 + r)*512 + kt + c8);
    }
    __syncthreads();
    #pragma unroll
    for (int ks = 0; ks < 2; ++ks){
      bf16x8 am[2], bn[2];
      #pragma unroll
      for (int x=0;x<2;++x) am[x] = *(const bf16x8*)&As[wm + x*16 + l15][ks*32 + quad*8];
      #pragma unroll
      for (int y=0;y<2;++y) bn[y] = *(const bf16x8*)&Bs[wn + y*16 + l15][ks*32 + quad*8];
      #pragma unroll
      for (int mt=0;mt<2;++mt)
        #pragma unroll
        for (int nt=0;nt<2;++nt)
          acc[mt][nt] = mfma16(am[mt], bn[nt], acc[mt][nt]);
    }
    __syncthreads();
  }
  #pragma unroll
  for (int mt=0;mt<2;++mt)
    #pragma unroll
    for (int r=0;r<4;++r){
      int m = m0 + wm + mt*16 + quad*4 + r;
      #pragma unroll
      for (int nt=0;nt<2;++nt)
        C[(size_t)m*512 + n0 + wn + nt*16 + l15] = acc[mt][nt][r];
    }
}

// ---------------- flash attention: LDS-gather bias, in-prologue MFMA LUT ----------------
// grid (32,8,2) x 256 thr. Square wave sub-tiles: QK (qh=w&1,kh=w>>1) -> 32q x 64k;
// PV -> 32q x 32d over full k=128. LUT 64x35 f32 in LDS (stride 35 = bank rotation);
// gathers hit LDS banks in parallel (TA-serialization was the ~100us wall, R3/R4 evidence).
// ids: coalesced int32, one-tile register lookahead (32 VGPRs; no K/V reg prefetch -> no spill).
__global__ __launch_bounds__(256,2) void k_attn(
    const bf16* __restrict__ Qp, const bf16* __restrict__ Kp,
    const bf16* __restrict__ Vt, const bf16* __restrict__ Rb,
    const int* __restrict__ ids, bf16* __restrict__ Out)
{
  // LDS: 18432 + 17408 + 17408 + 8960 + 512 = 62720 B -> 2 WG/CU
  __shared__ __align__(16) bf16 Ks[128][72];
  __shared__ __align__(16) bf16 Vs[64][136];
  __shared__ __align__(16) bf16 Ps[64][136];
  __shared__ float lut[64][35];
  __shared__ float lsum_s[128];

  const int t = threadIdx.x;
  const int b = blockIdx.z, h = blockIdx.y;
  const int q0 = blockIdx.x * 64;
  const int w = t >> 6, lane = t & 63, l15 = lane & 15, quad = lane >> 4;
  const int qh = w & 1, kh = w >> 1;

  const size_t idb = (size_t)b*SEQ*SEQ;

  // ---- prefetch tile-0 ids (latency hidden under LUT build) ----
  int nid[2][4][4];
  #pragma unroll
  for (int mt=0; mt<2; ++mt)
    #pragma unroll
    for (int nt=0; nt<4; ++nt)
      #pragma unroll
      for (int r=0; r<4; ++r)
        nid[mt][nt][r] = ids[idb + (size_t)(q0 + qh*32 + mt*16 + quad*4 + r)*SEQ
                             + kh*64 + nt*16 + l15];

  // ---- build LUT rows [16w, 16w+16) via MFMA: lut[q][p] = exp2(Qrel*ESCALE), p==0 -> 0 ----
  {
    const bf16* qbrow = Qp + (size_t)(b*SEQ + q0 + w*16 + l15)*EMBED + h*HD;
    bf16x8 ab0 = *(const bf16x8*)(qbrow + quad*8);
    bf16x8 ab1 = *(const bf16x8*)(qbrow + 32 + quad*8);
    const bf16* rh = Rb + h*3072;
    #pragma unroll
    for (int nt = 0; nt < 3; ++nt){
      bf16x8 r0 = *(const bf16x8*)(rh + (nt*16 + l15)*64 + quad*8);
      bf16x8 r1 = *(const bf16x8*)(rh + (nt*16 + l15)*64 + 32 + quad*8);
      f32x4 c = (f32x4){0.f,0.f,0.f,0.f};
      c = mfma16(ab0, r0, c);
      c = mfma16(ab1, r1, c);
      int p = nt*16 + l15;
      if (p < NPOS){
        #pragma unroll
        for (int r = 0; r < 4; ++r)
          lut[w*16 + quad*4 + r][p] = (p == 0) ? 0.f : exp2f(c[r]*ESCALE);
      }
    }
  }

  // ---- QK A-frags (reg-resident), rows qh*32+mt*16+l15 ----
  bf16x8 aq[2][2];
  #pragma unroll
  for (int mt = 0; mt < 2; ++mt){
    const bf16* qrow = Qp + (size_t)(b*SEQ + q0 + qh*32 + mt*16 + l15)*EMBED + h*HD;
    aq[mt][0] = *(const bf16x8*)(qrow + quad*8);
    aq[mt][1] = *(const bf16x8*)(qrow + 32 + quad*8);
  }

  const bf16* kbase = Kp + (size_t)b*SEQ*EMBED + h*HD;
  const bf16* vbase = Vt + (size_t)(b*NH + h)*HD*SEQ;

  f32x4 acc[2][2];
  #pragma unroll
  for (int mt=0;mt<2;++mt)
    #pragma unroll
    for (int nt=0;nt<2;++nt) acc[mt][nt] = (f32x4){0.f,0.f,0.f,0.f};
  float lsum[2][4] = {{0.f,0.f,0.f,0.f},{0.f,0.f,0.f,0.f}};

  for (int kt = 0; kt < 16; ++kt){
    const int k0 = kt * 128;
    // ---- stage K (128x64) and V^T (64x128) ----
    #pragma unroll
    for (int i = 0; i < 4; ++i){
      int lin = t + 256*i;
      int r = lin >> 3, c8 = (lin & 7) << 3;
      *(uint4*)&Ks[r][c8] = *(const uint4*)(kbase + (size_t)(k0 + r)*EMBED + c8);
    }
    #pragma unroll
    for (int i = 0; i < 4; ++i){
      int lin = t + 256*i;
      int d = lin >> 4, c8 = (lin & 15) << 3;
      *(uint4*)&Vs[d][c8] = *(const uint4*)(vbase + (size_t)d*SEQ + k0 + c8);
    }
    __syncthreads();   // covers LUT build on tile 0

    // ---- bias gathers from LDS LUT (banks in parallel; indices already resident) ----
    float wv[2][4][4];
    #pragma unroll
    for (int mt = 0; mt < 2; ++mt)
      #pragma unroll
      for (int nt = 0; nt < 4; ++nt)
        #pragma unroll
        for (int r = 0; r < 4; ++r)
          wv[mt][nt][r] = lut[qh*32 + mt*16 + quad*4 + r][nid[mt][nt][r]];

    // ---- prefetch next tile ids (VMEM flies under MFMA) ----
    if (kt < 15){
      #pragma unroll
      for (int mt = 0; mt < 2; ++mt)
        #pragma unroll
        for (int nt = 0; nt < 4; ++nt)
          #pragma unroll
          for (int r = 0; r < 4; ++r)
            nid[mt][nt][r] = ids[idb + (size_t)(q0 + qh*32 + mt*16 + quad*4 + r)*SEQ
                                 + (k0 + 128) + kh*64 + nt*16 + l15];
    }

    // ---- QK: wave computes 32q x 64k ----
    f32x4 sf[2][4];
    #pragma unroll
    for (int nt = 0; nt < 4; ++nt){
      bf16x8 bk0 = *(const bf16x8*)&Ks[kh*64 + nt*16 + l15][quad*8];
      bf16x8 bk1 = *(const bf16x8*)&Ks[kh*64 + nt*16 + l15][32 + quad*8];
      #pragma unroll
      for (int mt = 0; mt < 2; ++mt){
        f32x4 c = (f32x4){0.f,0.f,0.f,0.f};
        c = mfma16(aq[mt][0], bk0, c);
        c = mfma16(aq[mt][1], bk1, c);
        sf[mt][nt] = c;
      }
    }

    // ---- p = exp2(s*ESCALE)*wgt ; write Ps ----
    #pragma unroll
    for (int mt = 0; mt < 2; ++mt)
      #pragma unroll
      for (int nt = 0; nt < 4; ++nt)
        #pragma unroll
        for (int r = 0; r < 4; ++r){
          float p = exp2f(sf[mt][nt][r]*ESCALE) * wv[mt][nt][r];
          lsum[mt][r] += p;
          Ps[qh*32 + mt*16 + quad*4 + r][kh*64 + nt*16 + l15] = (bf16)p;
        }
    __syncthreads();   // Ps complete (cross-wave)

    // ---- PV: wave computes 32q x 32d over full k=128 ----
    #pragma unroll
    for (int kk = 0; kk < 4; ++kk){
      bf16x8 ap[2];
      #pragma unroll
      for (int mt = 0; mt < 2; ++mt)
        ap[mt] = *(const bf16x8*)&Ps[qh*32 + mt*16 + l15][kk*32 + quad*8];
      #pragma unroll
      for (int nt = 0; nt < 2; ++nt){
        bf16x8 bv = *(const bf16x8*)&Vs[kh*32 + nt*16 + l15][kk*32 + quad*8];
        #pragma unroll
        for (int mt = 0; mt < 2; ++mt)
          acc[mt][nt] = mfma16(ap[mt], bv, acc[mt][nt]);
      }
    }
    __syncthreads();   // Ks/Vs/Ps free for next tile
  }

  // ---- lsum exchange: reduce over l15, publish per (kh, q) ----
  #pragma unroll
  for (int mt = 0; mt < 2; ++mt)
    #pragma unroll
    for (int r = 0; r < 4; ++r){
      float v = lsum[mt][r];
      v += __shfl_xor(v, 1); v += __shfl_xor(v, 2);
      v += __shfl_xor(v, 4); v += __shfl_xor(v, 8);
      if (l15 == 0) lsum_s[kh*64 + qh*32 + mt*16 + quad*4 + r] = v;
    }
  __syncthreads();

  // ---- epilogue: normalize, store (b,s,h,d) bf16 ----
  #pragma unroll
  for (int mt = 0; mt < 2; ++mt){
    #pragma unroll
    for (int r = 0; r < 4; ++r){
      int ql = qh*32 + mt*16 + quad*4 + r;
      float inv = 1.f / (lsum_s[ql] + lsum_s[64 + ql]);
      #pragma unroll
      for (int nt = 0; nt < 2; ++nt){
        int d = kh*32 + nt*16 + l15;
        Out[(size_t)(b*SEQ + q0 + ql)*EMBED + h*HD + d] = (bf16)(acc[mt][nt][r]*inv);
      }
    }
  }
}

// ---------------- launch ----------------
extern "C" void kernel_launch(void* const* d_in, const int* in_sizes, int n_in,
                              void* d_out, int out_size, void* d_ws, size_t ws_size,
                              hipStream_t stream)
{
  (void)in_sizes; (void)n_in; (void)out_size;
  const float* Q  = (const float*)d_in[0];
  const float* K  = (const float*)d_in[1];
  const float* V  = (const float*)d_in[2];
  const int*   ID = (const int*)d_in[3];
  const float* Wq = (const float*)d_in[4];
  const float* Wk = (const float*)d_in[5];
  const float* Wv = (const float*)d_in[6];
  const float* Wo = (const float*)d_in[7];
  const float* RE = (const float*)d_in[8];
  float* out = (float*)d_out;

  const size_t MB = (size_t)1 << 20;
  if (ws_size < 36*MB) return;
  char* ws = (char*)d_ws;
  bf16*  Qb    = (bf16*)(ws + 0*MB);             // dead after proj -> AO overlay
  bf16*  Kb    = (bf16*)(ws + 4*MB);
  bf16*  Vb    = (bf16*)(ws + 8*MB);
  bf16*  Qp    = (bf16*)(ws + 12*MB);
  bf16*  Kp    = (bf16*)(ws + 16*MB);
  bf16*  Vt    = (bf16*)(ws + 20*MB);            // (b,h,d,s) written by proj z==2
  bf16*  Wall  = (bf16*)(ws + 24*MB);            // 2 MB (Wq',Wk',Wv',Wo')
  bf16*  Wop   = Wall + (size_t)3*262144;
  bf16*  Rb    = (bf16*)(ws + 26*MB);            // 48 KB
  bf16*  AO    = (bf16*)(ws + 0*MB);             // overlays Qb

  k_prep      <<<dim3(8032),    256, 0, stream>>>(Q, K, V, Wq, Wk, Wv, Wo, RE,
                                                  Qb, Kb, Vb, Wall, Rb);
  k_gemm_proj <<<dim3(8,32,3),  256, 0, stream>>>(Qb, Kb, Vb, Wall, Qp, Kp, Vt);
  k_attn      <<<dim3(32,8,2),  256, 0, stream>>>(Qp, Kp, Vt, Rb, ID, AO);
  k_gemm_out  <<<dim3(8,64),    256, 0, stream>>>(AO, Wop, out);
}